// Round 1
// baseline (239.777 us; speedup 1.0000x reference)
//
#include <hip/hip_runtime.h>

// Simple_window_attention collapses algebraically:
//   - ln2 is a LayerNorm over a size-1 axis -> output is exactly ln2_bias[0]
//     for ANY finite upstream values (x - mean(x) == 0.0 in IEEE; var == 0;
//     0/sqrt(eps)*scale + bias == bias).
//   - Hence the final matmul input is the constant bias2 broadcast over 2048
//     entries, and out[j] = bias2 * sum_i W_out[i][j].
// So the faithful kernel is a 2048x256 fp32 column-sum (2 MB read) scaled by
// ln2_bias[0]. x, W_qkv (192 MB!), ln1_*, attention all contribute exactly 0.

#define ROWS 2048
#define COLS 256

// Kernel A: partial column sums. 64 blocks x 256 threads; block b covers rows
// [b*32, b*32+32). Thread t: float4 col-group cg = t&63, sub-row sr = t>>6.
// Coalesced 16B/lane loads; LDS reduce 4 sub-partials -> 64x256 partials in ws.
__global__ void __launch_bounds__(256) colsum_partial_kernel(
    const float* __restrict__ W, float4* __restrict__ part) {
    const int b  = blockIdx.x;    // 0..63
    const int t  = threadIdx.x;   // 0..255
    const int cg = t & 63;        // float4 column group (cols 4cg..4cg+3)
    const int sr = t >> 6;        // 0..3
    const float4* W4 = (const float4*)W;  // view: [2048][64] float4
    float4 acc = make_float4(0.f, 0.f, 0.f, 0.f);
    const int r0 = b * 32 + sr * 8;
#pragma unroll
    for (int k = 0; k < 8; ++k) {
        float4 v = W4[(size_t)(r0 + k) * 64 + cg];
        acc.x += v.x; acc.y += v.y; acc.z += v.z; acc.w += v.w;
    }
    __shared__ float4 red[256];
    red[t] = acc;
    __syncthreads();
    if (sr == 0) {
        float4 a0 = red[cg], a1 = red[64 + cg], a2 = red[128 + cg], a3 = red[192 + cg];
        float4 s;
        s.x = a0.x + a1.x + a2.x + a3.x;
        s.y = a0.y + a1.y + a2.y + a3.y;
        s.z = a0.z + a1.z + a2.z + a3.z;
        s.w = a0.w + a1.w + a2.w + a3.w;
        part[b * 64 + cg] = s;  // floats [b*256 + 4cg .. +3]
    }
}

// Kernel B: final reduce over the 64 partial rows; scale by ln2_bias[0].
__global__ void __launch_bounds__(256) colsum_final_kernel(
    const float* __restrict__ part,   // [64][256]
    const float* __restrict__ bias2,  // ln2_bias (1 elem)
    float* __restrict__ out) {        // [256]
    const int j = threadIdx.x;  // 0..255
    float s = 0.f;
#pragma unroll 8
    for (int p = 0; p < 64; ++p) s += part[p * 256 + j];
    out[j] = bias2[0] * s;
}

extern "C" void kernel_launch(void* const* d_in, const int* in_sizes, int n_in,
                              void* d_out, int out_size, void* d_ws, size_t ws_size,
                              hipStream_t stream) {
    // setup_inputs order:
    // 0:x(8192) 1:W_qkv(8192*6144) 2:W_out(2048*256) 3:ln1_scale(16)
    // 4:ln1_bias(16) 5:ln2_scale(1) 6:ln2_bias(1) 7:carry(1)
    const float* W_out    = (const float*)d_in[2];
    const float* ln2_bias = (const float*)d_in[6];
    float* out = (float*)d_out;
    float4* part = (float4*)d_ws;  // needs 64*256*4 = 64 KB scratch

    colsum_partial_kernel<<<64, 256, 0, stream>>>(W_out, part);
    colsum_final_kernel<<<1, 256, 0, stream>>>((const float*)d_ws, ln2_bias, out);
}